// Round 2
// baseline (913.583 us; speedup 1.0000x reference)
//
#include <hip/hip_runtime.h>
#include <hip/hip_bf16.h>
#include <cstdint>
#include <cstddef>

typedef __bf16 bft;
typedef __bf16 bf16x8 __attribute__((ext_vector_type(8)));
typedef __bf16 bf16x4 __attribute__((ext_vector_type(4)));
typedef float  f32x4  __attribute__((ext_vector_type(4)));

#define MFMA(a, b, c) __builtin_amdgcn_mfma_f32_16x16x32_bf16(a, b, c, 0, 0, 0)

constexpr float SCALE = 0.17677669529663689f;  // hd^-0.5, hd=32
constexpr float INVS  = 5.656854249492381f;    // 1/SCALE (bias uses raw q)

// ---------------- fp32 -> bf16 convert (weights only) ----------------
__global__ __launch_bounds__(256) void cvt_kernel(const float* __restrict__ s,
                                                  bft* __restrict__ d, int n) {
  int stride = gridDim.x * blockDim.x;
  for (int i = blockIdx.x * blockDim.x + threadIdx.x; i * 4 < n; i += stride) {
    const float4 v = *reinterpret_cast<const float4*>(s + (size_t)i * 4);
    bf16x4 o = {(bft)v.x, (bft)v.y, (bft)v.z, (bft)v.w};
    *reinterpret_cast<bf16x4*>(d + (size_t)i * 4) = o;
  }
}

// ================= fused window-attention block =================
// 1 block = 1 window (64 tokens, C=256, 8 heads x hd=32). 4 waves; wave wv
// owns heads {wv, wv+4}. Phases:
//   P0: stage x (fp32->bf16) into LDS (QK alias, stride 272); preload A-frags
//   P1: QKV GEMM (M=64,N=768,K=256), B-frags streamed from L2; outputs to LDS
//       Q[h]/K[h] [64][36] (Q pre-scaled), V^T[h] [32][68]
//   P2: per head: QK^T + rel-pos bias (2 MFMAs + shfl) + softmax -> P (LDS,
//       stride 68, aliases dead Q/K of same head) -> PV -> O[h] (stride 36)
//   P3: proj GEMM (K=256 over 8 head-chunks), window_reverse fp32 store
// LDS: QK 73728 B + V 34816 B = 108544 B -> 1 block/CU, 4 waves.
__global__ __launch_bounds__(256, 1) void win_fused(
    const float* __restrict__ X, const bft* __restrict__ Wq,
    const float* __restrict__ Bq, const bft* __restrict__ Wp,
    const float* __restrict__ Bp, const float* __restrict__ rph,
    const float* __restrict__ rpw, float* __restrict__ Out) {
  __shared__ bft QK[36864];  // head h: Q @ h*4608, K @ h*4608+2304 (stride 36)
  __shared__ bft Vv[17408];  // head h: V^T @ h*2176, [c 32][tok] stride 68

  const int t = threadIdx.x, lane = t & 63, wv = t >> 6;
  const int l15 = lane & 15, l4 = lane >> 4;
  const int win = blockIdx.x;
  const int b = win >> 8, wh = (win >> 4) & 15, ww = win & 15;

  // ---- rel-pos table B-frags (cols = table row index 0..14, k = hd) ----
  bf16x8 rhf = {}, rwf = {};
  if (l15 < 15) {
    const float* th = rph + l15 * 32 + l4 * 8;
    const float* tw = rpw + l15 * 32 + l4 * 8;
#pragma unroll
    for (int j = 0; j < 8; ++j) {
      rhf[j] = (bft)(th[j] * INVS);
      rwf[j] = (bft)(tw[j] * INVS);
    }
  }

  // ---- P0: stage x window (rows of one window-y are 2048 contiguous floats)
  {
    const float* xw =
        X + ((size_t)b * 16384 + (size_t)(wh * 8) * 128 + ww * 8) * 256;
#pragma unroll
    for (int yy = 0; yy < 2; ++yy) {
      const int y = wv * 2 + yy;
      const float* src = xw + (size_t)y * 32768;
#pragma unroll
      for (int it = 0; it < 8; ++it) {
        float4 v = *reinterpret_cast<const float4*>(src + (it * 64 + lane) * 4);
        bf16x4 o = {(bft)v.x, (bft)v.y, (bft)v.z, (bft)v.w};
        *reinterpret_cast<bf16x4*>(&QK[(y * 8 + it) * 272 + lane * 4]) = o;
      }
    }
  }
  __syncthreads();

  // ---- preload x A-frags: af[m][kk] = rows m*16+l15, k = kk*32+l4*8 ----
  bf16x8 af[4][8];
#pragma unroll
  for (int m = 0; m < 4; ++m)
#pragma unroll
    for (int kk = 0; kk < 8; ++kk)
      af[m][kk] = *reinterpret_cast<const bf16x8*>(
          &QK[(m * 16 + l15) * 272 + kk * 32 + l4 * 8]);
  __syncthreads();  // Xs dead; QK region becomes Q/K storage

  // ---- P1: QKV GEMM ----
#pragma unroll
  for (int hh = 0; hh < 2; ++hh) {
    const int h = wv + hh * 4;
#pragma unroll
    for (int comp = 0; comp < 3; ++comp) {
#pragma unroll
      for (int half = 0; half < 2; ++half) {
        const int n0 = comp * 256 + h * 32 + half * 16;
        bf16x8 bw[8];
#pragma unroll
        for (int kk = 0; kk < 8; ++kk)
          bw[kk] = *reinterpret_cast<const bf16x8*>(
              &Wq[(size_t)(n0 + l15) * 256 + kk * 32 + l4 * 8]);
        f32x4 acc[4] = {};
#pragma unroll
        for (int kk = 0; kk < 8; ++kk)
#pragma unroll
          for (int m = 0; m < 4; ++m) acc[m] = MFMA(af[m][kk], bw[kk], acc[m]);
        const float bias = Bq[n0 + l15];
        if (comp == 0) {
#pragma unroll
          for (int m = 0; m < 4; ++m)
#pragma unroll
            for (int r = 0; r < 4; ++r)
              QK[h * 4608 + (m * 16 + l4 * 4 + r) * 36 + half * 16 + l15] =
                  (bft)((acc[m][r] + bias) * SCALE);
        } else if (comp == 1) {
#pragma unroll
          for (int m = 0; m < 4; ++m)
#pragma unroll
            for (int r = 0; r < 4; ++r)
              QK[h * 4608 + 2304 + (m * 16 + l4 * 4 + r) * 36 + half * 16 +
                 l15] = (bft)(acc[m][r] + bias);
        } else {
#pragma unroll
          for (int m = 0; m < 4; ++m) {
            bf16x4 pk = {(bft)(acc[m][0] + bias), (bft)(acc[m][1] + bias),
                         (bft)(acc[m][2] + bias), (bft)(acc[m][3] + bias)};
            *reinterpret_cast<bf16x4*>(
                &Vv[h * 2176 + (half * 16 + l15) * 68 + m * 16 + l4 * 4]) = pk;
          }
        }
      }
    }
  }
  __syncthreads();

  // ---- P2: attention per head ----
#pragma unroll
  for (int hh = 0; hh < 2; ++hh) {
    const int h = wv + hh * 4;
    const int qb = h * 4608, kb = qb + 2304, vb = h * 2176;
    bf16x8 qf[4], kf[4];
#pragma unroll
    for (int i = 0; i < 4; ++i) {
      bf16x4 lo, hi;
      lo = *reinterpret_cast<const bf16x4*>(&QK[qb + (i * 16 + l15) * 36 + l4 * 8]);
      hi = *reinterpret_cast<const bf16x4*>(&QK[qb + (i * 16 + l15) * 36 + l4 * 8 + 4]);
      qf[i] = __builtin_shufflevector(lo, hi, 0, 1, 2, 3, 4, 5, 6, 7);
      lo = *reinterpret_cast<const bf16x4*>(&QK[kb + (i * 16 + l15) * 36 + l4 * 8]);
      hi = *reinterpret_cast<const bf16x4*>(&QK[kb + (i * 16 + l15) * 36 + l4 * 8 + 4]);
      kf[i] = __builtin_shufflevector(lo, hi, 0, 1, 2, 3, 4, 5, 6, 7);
    }
    f32x4 s[4][4], gh[4], gw[4];
#pragma unroll
    for (int i = 0; i < 4; ++i) {
      f32x4 z = {};
      gh[i] = MFMA(qf[i], rhf, z);
      gw[i] = MFMA(qf[i], rwf, z);
#pragma unroll
      for (int j = 0; j < 4; ++j) {
        f32x4 z2 = {};
        s[i][j] = MFMA(qf[i], kf[j], z2);
      }
    }
    // softmax; rel-bias delivered via in-register shuffles from gh/gw D-frags
#pragma unroll
    for (int i = 0; i < 4; ++i)
#pragma unroll
      for (int r = 0; r < 4; ++r) {
        const int row = i * 16 + l4 * 4 + r;
        const int qy = row >> 3, qx = row & 7;
        const float bwv =
            __shfl(gw[i][r], (lane & 48) + (qx + 7 - (l15 & 7)));
        float v0[4], mx = -3.0e38f;
#pragma unroll
        for (int j = 0; j < 4; ++j) {
          const float bh =
              __shfl(gh[i][r], (lane & 48) + (qy + 7 - (j * 2 + (l15 >> 3))));
          v0[j] = s[i][j][r] + bh + bwv;
          mx = fmaxf(mx, v0[j]);
        }
        mx = fmaxf(mx, __shfl_xor(mx, 1));
        mx = fmaxf(mx, __shfl_xor(mx, 2));
        mx = fmaxf(mx, __shfl_xor(mx, 4));
        mx = fmaxf(mx, __shfl_xor(mx, 8));
        float sum = 0.f;
#pragma unroll
        for (int j = 0; j < 4; ++j) {
          v0[j] = __expf(v0[j] - mx);
          sum += v0[j];
        }
        sum += __shfl_xor(sum, 1);
        sum += __shfl_xor(sum, 2);
        sum += __shfl_xor(sum, 4);
        sum += __shfl_xor(sum, 8);
        const float inv = 1.0f / sum;
        // P -> head region (Q/K dead), stride 68
#pragma unroll
        for (int j = 0; j < 4; ++j)
          QK[qb + row * 68 + j * 16 + l15] = (bft)(v0[j] * inv);
      }
    __syncthreads();  // in-wave LDS RAW safety (cheap; uniform control flow)
    // PV: O(64x32) = P(64x64) @ V(64x32)
    bf16x8 pf[4][2], vf[2][2];
#pragma unroll
    for (int i = 0; i < 4; ++i)
#pragma unroll
      for (int kc = 0; kc < 2; ++kc) {
        bf16x4 lo = *reinterpret_cast<const bf16x4*>(
            &QK[qb + (i * 16 + l15) * 68 + kc * 32 + l4 * 8]);
        bf16x4 hi = *reinterpret_cast<const bf16x4*>(
            &QK[qb + (i * 16 + l15) * 68 + kc * 32 + l4 * 8 + 4]);
        pf[i][kc] = __builtin_shufflevector(lo, hi, 0, 1, 2, 3, 4, 5, 6, 7);
      }
#pragma unroll
    for (int j2 = 0; j2 < 2; ++j2)
#pragma unroll
      for (int kc = 0; kc < 2; ++kc) {
        bf16x4 lo = *reinterpret_cast<const bf16x4*>(
            &Vv[vb + (j2 * 16 + l15) * 68 + kc * 32 + l4 * 8]);
        bf16x4 hi = *reinterpret_cast<const bf16x4*>(
            &Vv[vb + (j2 * 16 + l15) * 68 + kc * 32 + l4 * 8 + 4]);
        vf[j2][kc] = __builtin_shufflevector(lo, hi, 0, 1, 2, 3, 4, 5, 6, 7);
      }
    f32x4 o[4][2] = {};
#pragma unroll
    for (int i = 0; i < 4; ++i)
#pragma unroll
      for (int j2 = 0; j2 < 2; ++j2) {
        o[i][j2] = MFMA(pf[i][0], vf[j2][0], o[i][j2]);
        o[i][j2] = MFMA(pf[i][1], vf[j2][1], o[i][j2]);
      }
    __syncthreads();  // P reads done before O overwrites region
    // O[h] -> head region base, stride 36 (proj input)
#pragma unroll
    for (int i = 0; i < 4; ++i)
#pragma unroll
      for (int j2 = 0; j2 < 2; ++j2)
#pragma unroll
        for (int r = 0; r < 4; ++r)
          QK[qb + (i * 16 + l4 * 4 + r) * 36 + j2 * 16 + l15] =
              (bft)o[i][j2][r];
  }
  __syncthreads();

  // ---- P3: proj GEMM + window_reverse ----
  float pbias[4];
#pragma unroll
  for (int n = 0; n < 4; ++n) pbias[n] = Bp[wv * 64 + n * 16 + l15];
  f32x4 po[4][4] = {};
#pragma unroll
  for (int sH = 0; sH < 8; ++sH) {
    bf16x8 oa[4];
#pragma unroll
    for (int m = 0; m < 4; ++m) {
      bf16x4 lo = *reinterpret_cast<const bf16x4*>(
          &QK[sH * 4608 + (m * 16 + l15) * 36 + l4 * 8]);
      bf16x4 hi = *reinterpret_cast<const bf16x4*>(
          &QK[sH * 4608 + (m * 16 + l15) * 36 + l4 * 8 + 4]);
      oa[m] = __builtin_shufflevector(lo, hi, 0, 1, 2, 3, 4, 5, 6, 7);
    }
#pragma unroll
    for (int n = 0; n < 4; ++n) {
      bf16x8 wb = *reinterpret_cast<const bf16x8*>(
          &Wp[(size_t)(wv * 64 + n * 16 + l15) * 256 + sH * 32 + l4 * 8]);
#pragma unroll
      for (int m = 0; m < 4; ++m) po[m][n] = MFMA(oa[m], wb, po[m][n]);
    }
  }
  float* ob = Out + ((size_t)b * 16384 + (size_t)(wh * 8) * 128 + ww * 8) * 256;
#pragma unroll
  for (int m = 0; m < 4; ++m)
#pragma unroll
    for (int r = 0; r < 4; ++r) {
      const int tok = m * 16 + l4 * 4 + r;
      float* og = ob + ((size_t)(tok >> 3) * 128 + (tok & 7)) * 256;
#pragma unroll
      for (int n = 0; n < 4; ++n)
        og[wv * 64 + n * 16 + l15] = po[m][n][r] + pbias[n];
    }
}

extern "C" void kernel_launch(void* const* d_in, const int* in_sizes, int n_in,
                              void* d_out, int out_size, void* d_ws,
                              size_t ws_size, hipStream_t stream) {
  const float* x      = (const float*)d_in[0];
  const float* qkv_w  = (const float*)d_in[1];
  const float* qkv_b  = (const float*)d_in[2];
  const float* proj_w = (const float*)d_in[3];
  const float* proj_b = (const float*)d_in[4];
  const float* rph    = (const float*)d_in[5];
  const float* rpw    = (const float*)d_in[6];
  float* out = (float*)d_out;

  // workspace: bf16 weights only (524,288 B)
  if (ws_size < 524288) return;
  bft* qw = (bft*)d_ws;                       // 196608 elems = 393216 B
  bft* pw = (bft*)((char*)d_ws + 393216);     // 65536 elems = 131072 B

  cvt_kernel<<<192, 256, 0, stream>>>(qkv_w, qw, 196608);
  cvt_kernel<<<64, 256, 0, stream>>>(proj_w, pw, 65536);
  win_fused<<<4096, 256, 0, stream>>>(x, qw, qkv_b, pw, proj_b, rph, rpw, out);
}

// Round 5
// 875.112 us; speedup vs baseline: 1.0440x; 1.0440x over previous
//
#include <hip/hip_runtime.h>
#include <hip/hip_bf16.h>
#include <cstdint>
#include <cstddef>

typedef __bf16 bft;
typedef __bf16 bf16x8 __attribute__((ext_vector_type(8)));
typedef __bf16 bf16x4 __attribute__((ext_vector_type(4)));
typedef float  f32x4  __attribute__((ext_vector_type(4)));

#define MFMA(a, b, c) __builtin_amdgcn_mfma_f32_16x16x32_bf16(a, b, c, 0, 0, 0)

constexpr float SCALE = 0.17677669529663689f;  // hd^-0.5, hd=32
constexpr float INVS  = 5.656854249492381f;    // 1/SCALE (bias uses raw q)

// ---------------- fp32 -> bf16 convert (weights only) ----------------
__global__ __launch_bounds__(256) void cvt_kernel(const float* __restrict__ s,
                                                  bft* __restrict__ d, int n) {
  int stride = gridDim.x * blockDim.x;
  for (int i = blockIdx.x * blockDim.x + threadIdx.x; i * 4 < n; i += stride) {
    const float4 v = *reinterpret_cast<const float4*>(s + (size_t)i * 4);
    bf16x4 o = {(bft)v.x, (bft)v.y, (bft)v.z, (bft)v.w};
    *reinterpret_cast<bf16x4*>(d + (size_t)i * 4) = o;
  }
}

// ================= fused window-attention block, v2 =================
// 1 block = 1 window. 4 waves. 2 head-passes: pass p, wave wv owns head
// h = wv + 4p. Per pass (NO cross-wave sync needed — all regions private):
//   af: x A-frags loaded straight from global (fp32->bf16 in-register)
//   P1: QKV GEMM for head h -> Q/K slot wv (stride 36), V^T slot h (stride 68)
//   P2: QK^T + rel-bias(MFMA+shfl) + softmax -> P over Q/K slot (stride 68)
//       -> PV -> O overwrites V slot h ([64][40])
// One __syncthreads, then P3: proj GEMM over 8 head-chunks + window_reverse.
// LDS: QK 4*9216 B + VO 8*5120 B = 77824 B -> 2 blocks/CU (8 waves/CU).
__global__ __launch_bounds__(256, 2) void win_fused(
    const float* __restrict__ X, const bft* __restrict__ Wq,
    const float* __restrict__ Bq, const bft* __restrict__ Wp,
    const float* __restrict__ Bp, const float* __restrict__ rph,
    const float* __restrict__ rpw, float* __restrict__ Out) {
  __shared__ alignas(16) bft QK[18432];  // 4 slots x 4608 elems
  __shared__ alignas(16) bft VO[20480];  // 8 slots x 2560 elems

  const int t = threadIdx.x, lane = t & 63, wv = t >> 6;
  const int l15 = lane & 15, l4 = lane >> 4;
  const int win = blockIdx.x;
  const int b = win >> 8, wh = (win >> 4) & 15, ww = win & 15;
  const float* xw =
      X + ((size_t)b * 16384 + (size_t)(wh * 8) * 128 + ww * 8) * 256;

  // rel-pos table B-frags (cols = table row idx 0..14; col 15 = 0)
  bf16x8 rhf = {}, rwf = {};
  if (l15 < 15) {
    const float* th = rph + l15 * 32 + l4 * 8;
    const float* tw = rpw + l15 * 32 + l4 * 8;
#pragma unroll
    for (int j = 0; j < 8; ++j) {
      rhf[j] = (bft)(th[j] * INVS);
      rwf[j] = (bft)(tw[j] * INVS);
    }
  }

  const int qb = wv * 4608, kb = qb + 2304;

#pragma unroll 1
  for (int p = 0; p < 2; ++p) {
    const int h = wv + p * 4;
    const int vb = h * 2560;

    // ---- x A-frags from global: af[m][kk] = rows m*16+l15, k=kk*32+l4*8 ----
    bf16x8 af[4][8];
#pragma unroll
    for (int m = 0; m < 4; ++m) {
      const int tok = m * 16 + l15;
      const float* rowp = xw + (size_t)((tok >> 3) * 128 + (tok & 7)) * 256;
#pragma unroll
      for (int kk = 0; kk < 8; ++kk) {
        const float* cp = rowp + kk * 32 + l4 * 8;
        float4 a = *reinterpret_cast<const float4*>(cp);
        float4 c2 = *reinterpret_cast<const float4*>(cp + 4);
        bf16x8 f = {(bft)a.x, (bft)a.y, (bft)a.z, (bft)a.w,
                    (bft)c2.x, (bft)c2.y, (bft)c2.z, (bft)c2.w};
        af[m][kk] = f;
      }
    }

    // ---- P1: QKV GEMM for head h ----
#pragma unroll
    for (int comp = 0; comp < 3; ++comp) {
#pragma unroll
      for (int half = 0; half < 2; ++half) {
        const int n0 = comp * 256 + h * 32 + half * 16;
        bf16x8 bw[8];
#pragma unroll
        for (int kk = 0; kk < 8; ++kk)
          bw[kk] = *reinterpret_cast<const bf16x8*>(
              &Wq[(size_t)(n0 + l15) * 256 + kk * 32 + l4 * 8]);
        f32x4 acc[4] = {};
#pragma unroll
        for (int kk = 0; kk < 8; ++kk)
#pragma unroll
          for (int m = 0; m < 4; ++m) acc[m] = MFMA(af[m][kk], bw[kk], acc[m]);
        const float bias = Bq[n0 + l15];
        if (comp == 0) {
#pragma unroll
          for (int m = 0; m < 4; ++m)
#pragma unroll
            for (int r = 0; r < 4; ++r)
              QK[qb + (m * 16 + l4 * 4 + r) * 36 + half * 16 + l15] =
                  (bft)((acc[m][r] + bias) * SCALE);
        } else if (comp == 1) {
#pragma unroll
          for (int m = 0; m < 4; ++m)
#pragma unroll
            for (int r = 0; r < 4; ++r)
              QK[kb + (m * 16 + l4 * 4 + r) * 36 + half * 16 + l15] =
                  (bft)(acc[m][r] + bias);
        } else {
#pragma unroll
          for (int m = 0; m < 4; ++m) {
            bf16x4 pk = {(bft)(acc[m][0] + bias), (bft)(acc[m][1] + bias),
                         (bft)(acc[m][2] + bias), (bft)(acc[m][3] + bias)};
            *reinterpret_cast<bf16x4*>(
                &VO[vb + (half * 16 + l15) * 68 + m * 16 + l4 * 4]) = pk;
          }
        }
      }
    }

    // ---- P2: attention for head h (wave-private; no block barrier) ----
    bf16x8 qf[4], kf[4];
#pragma unroll
    for (int i = 0; i < 4; ++i) {
      bf16x4 lo, hi;
      lo = *reinterpret_cast<const bf16x4*>(&QK[qb + (i * 16 + l15) * 36 + l4 * 8]);
      hi = *reinterpret_cast<const bf16x4*>(&QK[qb + (i * 16 + l15) * 36 + l4 * 8 + 4]);
      qf[i] = __builtin_shufflevector(lo, hi, 0, 1, 2, 3, 4, 5, 6, 7);
      lo = *reinterpret_cast<const bf16x4*>(&QK[kb + (i * 16 + l15) * 36 + l4 * 8]);
      hi = *reinterpret_cast<const bf16x4*>(&QK[kb + (i * 16 + l15) * 36 + l4 * 8 + 4]);
      kf[i] = __builtin_shufflevector(lo, hi, 0, 1, 2, 3, 4, 5, 6, 7);
    }
    f32x4 s[4][4], gh[4], gw[4];
#pragma unroll
    for (int i = 0; i < 4; ++i) {
      f32x4 z = {};
      gh[i] = MFMA(qf[i], rhf, z);
      gw[i] = MFMA(qf[i], rwf, z);
#pragma unroll
      for (int j = 0; j < 4; ++j) {
        f32x4 z2 = {};
        s[i][j] = MFMA(qf[i], kf[j], z2);
      }
    }
#pragma unroll
    for (int i = 0; i < 4; ++i)
#pragma unroll
      for (int r = 0; r < 4; ++r) {
        const int row = i * 16 + l4 * 4 + r;
        const int qy = row >> 3, qx = row & 7;
        const float bwv = __shfl(gw[i][r], (lane & 48) + (qx + 7 - (l15 & 7)));
        float v0[4], mx = -3.0e38f;
#pragma unroll
        for (int j = 0; j < 4; ++j) {
          const float bh =
              __shfl(gh[i][r], (lane & 48) + (qy + 7 - (j * 2 + (l15 >> 3))));
          v0[j] = s[i][j][r] + bh + bwv;
          mx = fmaxf(mx, v0[j]);
        }
        mx = fmaxf(mx, __shfl_xor(mx, 1));
        mx = fmaxf(mx, __shfl_xor(mx, 2));
        mx = fmaxf(mx, __shfl_xor(mx, 4));
        mx = fmaxf(mx, __shfl_xor(mx, 8));
        float sum = 0.f;
#pragma unroll
        for (int j = 0; j < 4; ++j) {
          v0[j] = __expf(v0[j] - mx);
          sum += v0[j];
        }
        sum += __shfl_xor(sum, 1);
        sum += __shfl_xor(sum, 2);
        sum += __shfl_xor(sum, 4);
        sum += __shfl_xor(sum, 8);
        const float inv = 1.0f / sum;
#pragma unroll
        for (int j = 0; j < 4; ++j)
          QK[qb + row * 68 + j * 16 + l15] = (bft)(v0[j] * inv);
      }
    // PV: O(64x32) = P(64x64) @ V(64x32)
    bf16x8 pf[4][2], vf[2][2];
#pragma unroll
    for (int i = 0; i < 4; ++i)
#pragma unroll
      for (int kc = 0; kc < 2; ++kc) {
        bf16x4 lo = *reinterpret_cast<const bf16x4*>(
            &QK[qb + (i * 16 + l15) * 68 + kc * 32 + l4 * 8]);
        bf16x4 hi = *reinterpret_cast<const bf16x4*>(
            &QK[qb + (i * 16 + l15) * 68 + kc * 32 + l4 * 8 + 4]);
        pf[i][kc] = __builtin_shufflevector(lo, hi, 0, 1, 2, 3, 4, 5, 6, 7);
      }
#pragma unroll
    for (int j2 = 0; j2 < 2; ++j2)
#pragma unroll
      for (int kc = 0; kc < 2; ++kc) {
        bf16x4 lo = *reinterpret_cast<const bf16x4*>(
            &VO[vb + (j2 * 16 + l15) * 68 + kc * 32 + l4 * 8]);
        bf16x4 hi = *reinterpret_cast<const bf16x4*>(
            &VO[vb + (j2 * 16 + l15) * 68 + kc * 32 + l4 * 8 + 4]);
        vf[j2][kc] = __builtin_shufflevector(lo, hi, 0, 1, 2, 3, 4, 5, 6, 7);
      }
    f32x4 o[4][2] = {};
#pragma unroll
    for (int i = 0; i < 4; ++i)
#pragma unroll
      for (int j2 = 0; j2 < 2; ++j2) {
        o[i][j2] = MFMA(pf[i][0], vf[j2][0], o[i][j2]);
        o[i][j2] = MFMA(pf[i][1], vf[j2][1], o[i][j2]);
      }
    // O overwrites V slot h: [64][40] (16B-aligned rows for P3 b128 reads)
#pragma unroll
    for (int i = 0; i < 4; ++i)
#pragma unroll
      for (int j2 = 0; j2 < 2; ++j2)
#pragma unroll
        for (int r = 0; r < 4; ++r)
          VO[vb + (i * 16 + l4 * 4 + r) * 40 + j2 * 16 + l15] =
              (bft)o[i][j2][r];
  }
  __syncthreads();  // the ONLY block barrier: all O slots ready

  // ---- P3: proj GEMM (K=256 over 8 head-chunks) + window_reverse ----
  f32x4 po[4][4] = {};
#pragma unroll
  for (int sH = 0; sH < 8; ++sH) {
    bf16x8 oa[4];
#pragma unroll
    for (int m = 0; m < 4; ++m)
      oa[m] = *reinterpret_cast<const bf16x8*>(
          &VO[sH * 2560 + (m * 16 + l15) * 40 + l4 * 8]);
#pragma unroll
    for (int n = 0; n < 4; ++n) {
      bf16x8 wb = *reinterpret_cast<const bf16x8*>(
          &Wp[(size_t)(wv * 64 + n * 16 + l15) * 256 + sH * 32 + l4 * 8]);
#pragma unroll
      for (int m = 0; m < 4; ++m) po[m][n] = MFMA(oa[m], wb, po[m][n]);
    }
  }
  float pbias[4];
#pragma unroll
  for (int n = 0; n < 4; ++n) pbias[n] = Bp[wv * 64 + n * 16 + l15];
  float* ob = Out + ((size_t)b * 16384 + (size_t)(wh * 8) * 128 + ww * 8) * 256;
#pragma unroll
  for (int m = 0; m < 4; ++m)
#pragma unroll
    for (int r = 0; r < 4; ++r) {
      const int tok = m * 16 + l4 * 4 + r;
      float* og = ob + ((size_t)(tok >> 3) * 128 + (tok & 7)) * 256;
#pragma unroll
      for (int n = 0; n < 4; ++n)
        og[wv * 64 + n * 16 + l15] = po[m][n][r] + pbias[n];
    }
}

extern "C" void kernel_launch(void* const* d_in, const int* in_sizes, int n_in,
                              void* d_out, int out_size, void* d_ws,
                              size_t ws_size, hipStream_t stream) {
  const float* x      = (const float*)d_in[0];
  const float* qkv_w  = (const float*)d_in[1];
  const float* qkv_b  = (const float*)d_in[2];
  const float* proj_w = (const float*)d_in[3];
  const float* proj_b = (const float*)d_in[4];
  const float* rph    = (const float*)d_in[5];
  const float* rpw    = (const float*)d_in[6];
  float* out = (float*)d_out;

  if (ws_size < 524288) return;
  bft* qw = (bft*)d_ws;                    // qkv_w bf16: 196608 elems
  bft* pw = (bft*)((char*)d_ws + 393216);  // proj_w bf16: 65536 elems

  cvt_kernel<<<192, 256, 0, stream>>>(qkv_w, qw, 196608);
  cvt_kernel<<<64, 256, 0, stream>>>(proj_w, pw, 65536);
  win_fused<<<4096, 256, 0, stream>>>(x, qw, qkv_b, pw, proj_b, rph, rpw, out);
}